// Round 16
// baseline (216.540 us; speedup 1.0000x reference)
//
#include <hip/hip_runtime.h>
#include <hip/hip_bf16.h>

// ---------------------------------------------------------------------------
// Fused causal MHA forward: x[B,T,C] fp32, w_qkv[3C,C] fp32, w_out[C,C] fp32
// B=4 T=2048 C=1024 H=16 hd=64.  All matmuls in bf16 MFMA, fp32 accumulate.
// fused convert | GEMM qkv | V-transpose | flash-attn (static map) | proj.
// R15 + attn: unified PV (each V-fragment read once, feeds both 32-row
// halves) and max3-fused max trees.
// ---------------------------------------------------------------------------

typedef __attribute__((ext_vector_type(8))) short bf16x8;
typedef __attribute__((ext_vector_type(4))) float f32x4;
typedef __attribute__((ext_vector_type(16))) float f32x16;
typedef __attribute__((ext_vector_type(2))) unsigned uint2v;

#define GLOBAL_AS __attribute__((address_space(1)))
#define LDS_AS __attribute__((address_space(3)))

__device__ __forceinline__ unsigned short f2b_rne(float f) {
  unsigned u = __float_as_uint(f);
  unsigned r = u + 0x7fffu + ((u >> 16) & 1u);
  return (unsigned short)(r >> 16);
}

__device__ __forceinline__ unsigned cvt_pk_bf16(float lo, float hi) {
  unsigned r;
  asm("v_cvt_pk_bf16_f32 %0, %1, %2" : "=v"(r) : "v"(lo), "v"(hi));
  return r;
}

__device__ __forceinline__ void gload_lds16(const void* g, void* l) {
  __builtin_amdgcn_global_load_lds((const GLOBAL_AS void*)g, (LDS_AS void*)l, 16, 0, 0);
}

// ---------------------------------------------------------------------------
// Fused fp32 -> bf16 conversion of all three inputs.
// ---------------------------------------------------------------------------
__global__ void fused_convert(const float* __restrict__ x,
                              const float* __restrict__ wqkv,
                              const float* __restrict__ wout,
                              unsigned short* __restrict__ xb,
                              unsigned short* __restrict__ wqkvb,
                              unsigned short* __restrict__ woutb) {
  const int nx = 8192 * 1024 / 4, nq = 3072 * 1024 / 4, nw = 1024 * 1024 / 4;
  const int ntot = nx + nq + nw;
  int i = blockIdx.x * blockDim.x + threadIdx.x;
  int stride = gridDim.x * blockDim.x;
  for (; i < ntot; i += stride) {
    const float* src;
    unsigned short* dst;
    int j = i;
    if (j < nx) {
      src = x; dst = xb;
    } else if ((j -= nx) < nq) {
      src = wqkv; dst = wqkvb;
    } else {
      j -= nq; src = wout; dst = woutb;
    }
    float4 v = reinterpret_cast<const float4*>(src)[j];
    ushort4 o;
    o.x = f2b_rne(v.x); o.y = f2b_rne(v.y);
    o.z = f2b_rne(v.z); o.w = f2b_rne(v.w);
    reinterpret_cast<ushort4*>(dst)[j] = o;
  }
}

// ---------------------------------------------------------------------------
// V transpose: qkv V-block rows -> vt[bh][d][T] via swizzled 64x64 LDS tile.
// ---------------------------------------------------------------------------
__global__ __launch_bounds__(256)
void v_transpose(const unsigned short* __restrict__ qkv,
                 unsigned short* __restrict__ vt) {
  __shared__ __align__(16) unsigned short Ts[64][64];
  const int tc = blockIdx.x, bh = blockIdx.y;
  const int b = bh >> 4, hed = bh & 15;
  const int t0 = tc * 64;
  const int tid = threadIdx.x;
  {
    const int r = tid >> 2, cb = (tid & 3) * 2;
    const unsigned short* src =
        qkv + (size_t)(b * 2048 + t0 + r) * 3072 + 2048 + hed * 64;
    bf16x8 v0 = *(const bf16x8*)(src + cb * 8);
    bf16x8 v1 = *(const bf16x8*)(src + cb * 8 + 8);
    *(bf16x8*)&Ts[r][(cb ^ (r & 7)) * 8] = v0;
    *(bf16x8*)&Ts[r][((cb + 1) ^ (r & 7)) * 8] = v1;
  }
  __syncthreads();
  const int d = tid >> 2;
  unsigned short* dst = vt + ((size_t)bh * 64 + d) * 2048 + t0;
#pragma unroll
  for (int tb2 = 0; tb2 < 2; ++tb2) {
    int tb = (tid & 3) * 2 + tb2;
    union { unsigned short s[8]; bf16x8 v; } o;
#pragma unroll
    for (int i = 0; i < 8; ++i) {
      int row = tb * 8 + i;
      o.s[i] = Ts[row][(((d >> 3) ^ (row & 7)) * 8) + (d & 7)];
    }
    *(bf16x8*)(dst + tb * 8) = o.v;
  }
}

// ---------------------------------------------------------------------------
// Big GEMM template: C[M,N] = A[M,1024] * B[N,1024]^T.
// 256x128 tile, 8 waves (4Mx2N), BK=64, mfma_32x32x16, counted-vmcnt loop.
// ---------------------------------------------------------------------------
template <int N, int OUT_BF16>
__global__ __launch_bounds__(512)
void gemm_big(const unsigned short* __restrict__ A,
              const unsigned short* __restrict__ B,
              void* __restrict__ Cout) {
  const int K = 1024;
  __shared__ __align__(16) unsigned short As[2][2][128 * 64];
  __shared__ __align__(16) unsigned short Bs[2][128 * 64];

  const int tid = threadIdx.x, wid = tid >> 6, lane = tid & 63;
  const int l31 = lane & 31, h = lane >> 5;
  const int NBX = N / 128;
  const int nwg8 = (int)gridDim.x >> 3;
  const int wgid = ((int)blockIdx.x & 7) * nwg8 + ((int)blockIdx.x >> 3);
  const int bx = wgid % NBX, by = wgid / NBX;
  const int m0 = by * 256, n0 = bx * 128;
  const int wr = wid >> 1, wc = wid & 1;

  auto stage = [&](int t, int buf) {
    const int k0 = t * 64;
    const int r8 = lane >> 3;
    const int blk = (lane & 7) ^ r8;
#pragma unroll
    for (int hh = 0; hh < 2; ++hh)
#pragma unroll
      for (int r = 0; r < 2; ++r) {
        int row = r * 64 + wid * 8 + r8;
        gload_lds16(A + (size_t)(m0 + hh * 128 + row) * K + k0 + blk * 8,
                    &As[buf][hh][r * 4096 + wid * 512]);
      }
#pragma unroll
    for (int r = 0; r < 2; ++r) {
      int row = r * 64 + wid * 8 + r8;
      gload_lds16(B + (size_t)(n0 + row) * K + k0 + blk * 8,
                  &Bs[buf][r * 4096 + wid * 512]);
    }
  };

  f32x16 acc[2][2] = {};

  stage(0, 0);

  int cur = 0;
  for (int t = 0; t < 16; ++t) {
    __builtin_amdgcn_s_barrier();
    if (t + 1 < 16) {
      stage(t + 1, cur ^ 1);
      asm volatile("s_waitcnt vmcnt(6)" ::: "memory");
    } else {
      asm volatile("s_waitcnt vmcnt(0)" ::: "memory");
    }
    __builtin_amdgcn_s_barrier();
    __builtin_amdgcn_sched_barrier(0);

    bf16x8 af[2][4], bfr[2][4];
#pragma unroll
    for (int mi = 0; mi < 2; ++mi) {
      int row = (wr & 1) * 64 + mi * 32 + l31;
#pragma unroll
      for (int ks = 0; ks < 4; ++ks) {
        int chunk = (ks * 2 + h) ^ (row & 7);
        af[mi][ks] = *(const bf16x8*)&As[cur][wr >> 1][row * 64 + chunk * 8];
      }
    }
#pragma unroll
    for (int ni = 0; ni < 2; ++ni) {
      int row = wc * 64 + ni * 32 + l31;
#pragma unroll
      for (int ks = 0; ks < 4; ++ks) {
        int chunk = (ks * 2 + h) ^ (row & 7);
        bfr[ni][ks] = *(const bf16x8*)&Bs[cur][row * 64 + chunk * 8];
      }
    }
    __builtin_amdgcn_s_setprio(1);
#pragma unroll
    for (int ks = 0; ks < 4; ++ks)
#pragma unroll
      for (int mi = 0; mi < 2; ++mi)
#pragma unroll
        for (int ni = 0; ni < 2; ++ni)
          acc[mi][ni] = __builtin_amdgcn_mfma_f32_32x32x16_bf16(
              af[mi][ks], bfr[ni][ks], acc[mi][ni], 0, 0, 0);
    __builtin_amdgcn_s_setprio(0);
    cur ^= 1;
  }

#pragma unroll
  for (int mi = 0; mi < 2; ++mi)
#pragma unroll
    for (int ni = 0; ni < 2; ++ni)
#pragma unroll
      for (int reg = 0; reg < 16; ++reg) {
        int row = m0 + wr * 64 + mi * 32 + (reg & 3) + 8 * (reg >> 2) + 4 * h;
        int col = n0 + wc * 64 + ni * 32 + l31;
        if (OUT_BF16)
          ((unsigned short*)Cout)[(size_t)row * N + col] =
              f2b_rne(acc[mi][ni][reg]);
        else
          ((float*)Cout)[(size_t)row * N + col] = acc[mi][ni][reg];
      }
}

// ---------------------------------------------------------------------------
// Flash attention fwd, causal; swapped-QK^T 32x32; 64 q-rows per wave.
// Unified PV: softmax for both 32-row halves first (pk0, pk1 live), then one
// PV loop reading each V-fragment ONCE and feeding both halves' MFMAs.
// Static XCD map (R12).  Plain launch_bounds(256): VGPR may exceed 128 but
// stays <=256 so 2 blocks/CU residency is kept.
// ---------------------------------------------------------------------------
__global__ __launch_bounds__(256)
void attn_fwd(const unsigned short* __restrict__ qkv,
              const unsigned short* __restrict__ vt,
              unsigned short* __restrict__ out) {
  const int T = 2048, C3 = 3072;
  __shared__ __align__(16) unsigned short Ks[2][64][64];  // [kv][d] swizzled
  __shared__ __align__(16) unsigned short Vs[2][64][64];  // [d][kv] swizzled
  __shared__ float Bc[4][32];                             // per-wave broadcast

  const int tid = threadIdx.x, w = tid >> 6, lane = tid & 63;
  const int l31 = lane & 31, h = lane >> 5;
  const int wgid = (blockIdx.x & 7) * 64 + (blockIdx.x >> 3);
  const int local = wgid & 63, xcd = wgid >> 6;
  const int qidx = local >> 3, bhl = local & 7;
  const int bh = xcd * 8 + bhl;
  const int qt = (qidx < 4) ? (7 - qidx) : (qidx - 4);
  const int b = bh >> 4, hed = bh & 15;
  const int qw = qt * 256 + w * 64;
  const size_t rowbase = (size_t)b * T * C3;
  const int hoff = hed * 64;
  const unsigned short* vbase = vt + (size_t)bh * 64 * 2048;
  const float c2 = 0.18033688f;  // 0.125 * log2(e)

  auto stageK = [&](int kv0, int buf) {
#pragma unroll
    for (int pp = 0; pp < 2; ++pp) {
      int chunk = w * 2 + pp;
      int row = chunk * 8 + (lane >> 3);
      int blk = (lane & 7) ^ (lane >> 3);
      gload_lds16(
          qkv + rowbase + (size_t)(kv0 + row) * C3 + 1024 + hoff + blk * 8,
          &Ks[buf][chunk * 8][0]);
    }
  };
  auto stageV = [&](int kv0, int buf) {
#pragma unroll
    for (int pp = 0; pp < 2; ++pp) {
      int chunk = w * 2 + pp;
      int drow = chunk * 8 + (lane >> 3);
      int blk = (lane & 7) ^ (lane >> 3);
      gload_lds16(vbase + (size_t)drow * 2048 + kv0 + blk * 8,
                  &Vs[buf][chunk * 8][0]);
    }
  };

  bf16x8 qf0[4], qf1[4];
  {
    const unsigned short* qp0 =
        qkv + rowbase + (size_t)(qw + l31) * C3 + hoff + h * 8;
    const unsigned short* qp1 = qp0 + 32 * C3;
#pragma unroll
    for (int s = 0; s < 4; ++s) {
      qf0[s] = *(const bf16x8*)(qp0 + 16 * s);
      qf1[s] = *(const bf16x8*)(qp1 + 16 * s);
    }
  }

  f32x16 oacc0[2] = {}, oacc1[2] = {};
  float mr0 = -1e30f, mr1 = -1e30f, sum0 = 0.f, sum1 = 0.f;

  stageK(0, 0);
  stageV(0, 0);

  // softmax for one 32-row half: mask, max (max3 chains), defer-rescale,
  // exp2, sum, pack to pk[16].  No PV here (unified below).
  auto do_softmax = [&](f32x16 (&sacc)[2], int qx, float& mr, float& sm,
                        f32x16 (&oc)[2], int t, int kv0,
                        unsigned (&pk)[16]) {
    if (kv0 + 64 > qx) {
      int q_abs = qx + l31;
#pragma unroll
      for (int kt = 0; kt < 2; ++kt)
#pragma unroll
        for (int r = 0; r < 16; ++r) {
          int kv_abs = kv0 + kt * 32 + (r & 3) + 8 * (r >> 2) + 4 * h;
          if (kv_abs > q_abs) sacc[kt][r] = -1e30f;
        }
    }
    // max via fused max3 chains (15 v_max3 + 1 shfl)
    float tm = fmaxf(sacc[0][0], sacc[0][1]);
#pragma unroll
    for (int r = 2; r < 16; r += 2)
      tm = fmaxf(fmaxf(tm, sacc[0][r]), sacc[0][r + 1]);
#pragma unroll
    for (int r = 0; r < 16; r += 2)
      tm = fmaxf(fmaxf(tm, sacc[1][r]), sacc[1][r + 1]);
    tm = fmaxf(tm, __shfl_xor(tm, 32));
    if (t == 0) {
      mr = tm;
    } else if (!__all(tm <= mr + 16.0f)) {
      float mnew = fmaxf(mr, tm);
      float corr = __builtin_amdgcn_exp2f((mr - mnew) * c2);
      sm *= corr;
      if (h == 0) Bc[w][l31] = corr;
      mr = mnew;
      asm volatile("s_waitcnt lgkmcnt(0)" ::: "memory");
#pragma unroll
      for (int r = 0; r < 16; ++r) {
        float cr = Bc[w][(r & 3) + 8 * (r >> 2) + 4 * h];
        oc[0][r] *= cr;
        oc[1][r] *= cr;
      }
    }
    float m2 = mr * c2;
    float s0 = 0.f, s1 = 0.f, s2 = 0.f, s3 = 0.f;
#pragma unroll
    for (int kt = 0; kt < 2; ++kt)
#pragma unroll
      for (int r = 0; r < 16; r += 4) {
        float p0 = __builtin_amdgcn_exp2f(fmaf(sacc[kt][r + 0], c2, -m2));
        float p1 = __builtin_amdgcn_exp2f(fmaf(sacc[kt][r + 1], c2, -m2));
        float p2 = __builtin_amdgcn_exp2f(fmaf(sacc[kt][r + 2], c2, -m2));
        float p3 = __builtin_amdgcn_exp2f(fmaf(sacc[kt][r + 3], c2, -m2));
        sacc[kt][r + 0] = p0; sacc[kt][r + 1] = p1;
        sacc[kt][r + 2] = p2; sacc[kt][r + 3] = p3;
        s0 += p0; s1 += p1; s2 += p2; s3 += p3;
      }
    float sl = (s0 + s1) + (s2 + s3);
    sm += sl + __shfl_xor(sl, 32);
#pragma unroll
    for (int kt = 0; kt < 2; ++kt)
#pragma unroll
      for (int r = 0; r < 16; r += 2)
        pk[kt * 8 + (r >> 1)] = cvt_pk_bf16(sacc[kt][r], sacc[kt][r + 1]);
  };

  int cur = 0;
  const int ntiles = 4 * qt + 4;
  for (int t = 0; t < ntiles; ++t) {
    const int kv0 = t * 64;
    __builtin_amdgcn_s_barrier();
    if (t + 1 < ntiles) {
      stageK(kv0 + 64, cur ^ 1);
      stageV(kv0 + 64, cur ^ 1);
      asm volatile("s_waitcnt vmcnt(4)" ::: "memory");
    } else {
      asm volatile("s_waitcnt vmcnt(0)" ::: "memory");
    }
    __builtin_amdgcn_s_barrier();
    __builtin_amdgcn_sched_barrier(0);

    if (kv0 <= qw) {
      // ---- S^T for both halves; each K-frag read once, used twice ----
      f32x16 sacc0[2] = {}, sacc1[2] = {};
      __builtin_amdgcn_s_setprio(1);
#pragma unroll
      for (int s = 0; s < 4; ++s) {
#pragma unroll
        for (int kt = 0; kt < 2; ++kt) {
          int row = kt * 32 + l31;
          int blk = (2 * s + h) ^ (row & 7);
          bf16x8 kf = *(const bf16x8*)&Ks[cur][row][blk * 8];
          sacc0[kt] = __builtin_amdgcn_mfma_f32_32x32x16_bf16(kf, qf0[s],
                                                              sacc0[kt], 0, 0, 0);
          sacc1[kt] = __builtin_amdgcn_mfma_f32_32x32x16_bf16(kf, qf1[s],
                                                              sacc1[kt], 0, 0, 0);
        }
      }
      __builtin_amdgcn_s_setprio(0);
      // ---- softmax both halves (pk0, pk1 stay live) ----
      unsigned pk0[16], pk1[16];
      do_softmax(sacc0, qw, mr0, sum0, oacc0, t, kv0, pk0);
      do_softmax(sacc1, qw + 32, mr1, sum1, oacc1, t, kv0, pk1);
      // ---- unified PV: each V-fragment read ONCE, feeds both halves ----
      __builtin_amdgcn_s_setprio(1);
#pragma unroll
      for (int sg = 0; sg < 4; ++sg) {
        const int kt = sg >> 1, s = sg & 1;
        const int base = kt * 8 + 4 * s;
        uint2v a02 = __builtin_amdgcn_permlane32_swap(pk0[base], pk0[base + 2],
                                                      false, false);
        uint2v a13 = __builtin_amdgcn_permlane32_swap(pk0[base + 1],
                                                      pk0[base + 3],
                                                      false, false);
        uint2v b02 = __builtin_amdgcn_permlane32_swap(pk1[base], pk1[base + 2],
                                                      false, false);
        uint2v b13 = __builtin_amdgcn_permlane32_swap(pk1[base + 1],
                                                      pk1[base + 3],
                                                      false, false);
        union { unsigned u[4]; bf16x8 v; } A0, A1;
        A0.u[0] = a02.x; A0.u[1] = a13.x; A0.u[2] = a02.y; A0.u[3] = a13.y;
        A1.u[0] = b02.x; A1.u[1] = b13.x; A1.u[2] = b02.y; A1.u[3] = b13.y;
#pragma unroll
        for (int dt = 0; dt < 2; ++dt) {
          int d = dt * 32 + l31;
          int blk = (2 * sg + h) ^ (d & 7);
          bf16x8 vf = *(const bf16x8*)&Vs[cur][d][blk * 8];
          oacc0[dt] = __builtin_amdgcn_mfma_f32_32x32x16_bf16(A0.v, vf,
                                                              oacc0[dt], 0, 0, 0);
          oacc1[dt] = __builtin_amdgcn_mfma_f32_32x32x16_bf16(A1.v, vf,
                                                              oacc1[dt], 0, 0, 0);
        }
      }
      __builtin_amdgcn_s_setprio(0);
    }
    cur ^= 1;
  }

#pragma unroll
  for (int X = 0; X < 2; ++X) {
    float sm = X ? sum1 : sum0;
    if (h == 0) Bc[w][l31] = 1.0f / sm;
    asm volatile("s_waitcnt lgkmcnt(0)" ::: "memory");
#pragma unroll
    for (int r = 0; r < 16; ++r) {
      int ql = (r & 3) + 8 * (r >> 2) + 4 * h;
      float inv = Bc[w][ql];
      int q_abs = qw + 32 * X + ql;
#pragma unroll
      for (int dt = 0; dt < 2; ++dt) {
        float v = (X ? oacc1 : oacc0)[dt][r] * inv;
        out[(size_t)(b * T + q_abs) * 1024 + hoff + dt * 32 + l31] =
            f2b_rne(v);
      }
    }
    __builtin_amdgcn_s_barrier();  // Bc reuse between halves
  }
}

// ---------------------------------------------------------------------------
extern "C" void kernel_launch(void* const* d_in, const int* in_sizes, int n_in,
                              void* d_out, int out_size, void* d_ws,
                              size_t ws_size, hipStream_t stream) {
  const float* x = (const float*)d_in[0];      // [4,2048,1024]
  const float* w_qkv = (const float*)d_in[1];  // [3072,1024]
  const float* w_out = (const float*)d_in[2];  // [1024,1024]
  float* out = (float*)d_out;                  // [4,2048,1024] fp32

  const int M = 8192, C = 1024, C3 = 3072;

  unsigned short* xb = (unsigned short*)d_ws;      // M*C  (reused as attno)
  unsigned short* wqkvb = xb + (size_t)M * C;      // C3*C
  unsigned short* woutb = wqkvb + (size_t)C3 * C;  // C*C
  unsigned short* qkv = woutb + (size_t)C * C;     // M*C3
  unsigned short* vtb = qkv + (size_t)M * C3;      // B*H*64*T = M*C
  unsigned short* attno = xb;                      // alias: xb dead post-GEMM1

  fused_convert<<<2048, 256, 0, stream>>>(x, w_qkv, w_out, xb, wqkvb, woutb);

  gemm_big<3072, 1><<<768, 512, 0, stream>>>(xb, wqkvb, qkv);

  v_transpose<<<dim3(32, 64), 256, 0, stream>>>(qkv, vtb);

  attn_fwd<<<512, 256, 0, stream>>>(qkv, vtb, attno);

  gemm_big<1024, 0><<<256, 512, 0, stream>>>(attno, woutb, out);
}

// Round 17
// 186.361 us; speedup vs baseline: 1.1619x; 1.1619x over previous
//
#include <hip/hip_runtime.h>
#include <hip/hip_bf16.h>

// ---------------------------------------------------------------------------
// Fused causal MHA forward: x[B,T,C] fp32, w_qkv[3C,C] fp32, w_out[C,C] fp32
// B=4 T=2048 C=1024 H=16 hd=64.  All matmuls in bf16 MFMA, fp32 accumulate.
// fused convert | GEMM qkv | V-transpose | flash-attn (static map) | proj.
// R15-measured best configuration (186.7us): R12 attn + R13 fused convert.
// R16's unified-PV reverted (VGPR 172 > 128 halved occupancy: 84.5->116.5us).
// ---------------------------------------------------------------------------

typedef __attribute__((ext_vector_type(8))) short bf16x8;
typedef __attribute__((ext_vector_type(4))) float f32x4;
typedef __attribute__((ext_vector_type(16))) float f32x16;
typedef __attribute__((ext_vector_type(2))) unsigned uint2v;

#define GLOBAL_AS __attribute__((address_space(1)))
#define LDS_AS __attribute__((address_space(3)))

__device__ __forceinline__ unsigned short f2b_rne(float f) {
  unsigned u = __float_as_uint(f);
  unsigned r = u + 0x7fffu + ((u >> 16) & 1u);
  return (unsigned short)(r >> 16);
}

__device__ __forceinline__ unsigned cvt_pk_bf16(float lo, float hi) {
  unsigned r;
  asm("v_cvt_pk_bf16_f32 %0, %1, %2" : "=v"(r) : "v"(lo), "v"(hi));
  return r;
}

__device__ __forceinline__ void gload_lds16(const void* g, void* l) {
  __builtin_amdgcn_global_load_lds((const GLOBAL_AS void*)g, (LDS_AS void*)l, 16, 0, 0);
}

// ---------------------------------------------------------------------------
// Fused fp32 -> bf16 conversion of all three inputs.
// ---------------------------------------------------------------------------
__global__ void fused_convert(const float* __restrict__ x,
                              const float* __restrict__ wqkv,
                              const float* __restrict__ wout,
                              unsigned short* __restrict__ xb,
                              unsigned short* __restrict__ wqkvb,
                              unsigned short* __restrict__ woutb) {
  const int nx = 8192 * 1024 / 4, nq = 3072 * 1024 / 4, nw = 1024 * 1024 / 4;
  const int ntot = nx + nq + nw;
  int i = blockIdx.x * blockDim.x + threadIdx.x;
  int stride = gridDim.x * blockDim.x;
  for (; i < ntot; i += stride) {
    const float* src;
    unsigned short* dst;
    int j = i;
    if (j < nx) {
      src = x; dst = xb;
    } else if ((j -= nx) < nq) {
      src = wqkv; dst = wqkvb;
    } else {
      j -= nq; src = wout; dst = woutb;
    }
    float4 v = reinterpret_cast<const float4*>(src)[j];
    ushort4 o;
    o.x = f2b_rne(v.x); o.y = f2b_rne(v.y);
    o.z = f2b_rne(v.z); o.w = f2b_rne(v.w);
    reinterpret_cast<ushort4*>(dst)[j] = o;
  }
}

// ---------------------------------------------------------------------------
// V transpose: qkv V-block rows -> vt[bh][d][T] via swizzled 64x64 LDS tile.
// ---------------------------------------------------------------------------
__global__ __launch_bounds__(256)
void v_transpose(const unsigned short* __restrict__ qkv,
                 unsigned short* __restrict__ vt) {
  __shared__ __align__(16) unsigned short Ts[64][64];
  const int tc = blockIdx.x, bh = blockIdx.y;
  const int b = bh >> 4, hed = bh & 15;
  const int t0 = tc * 64;
  const int tid = threadIdx.x;
  {
    const int r = tid >> 2, cb = (tid & 3) * 2;
    const unsigned short* src =
        qkv + (size_t)(b * 2048 + t0 + r) * 3072 + 2048 + hed * 64;
    bf16x8 v0 = *(const bf16x8*)(src + cb * 8);
    bf16x8 v1 = *(const bf16x8*)(src + cb * 8 + 8);
    *(bf16x8*)&Ts[r][(cb ^ (r & 7)) * 8] = v0;
    *(bf16x8*)&Ts[r][((cb + 1) ^ (r & 7)) * 8] = v1;
  }
  __syncthreads();
  const int d = tid >> 2;
  unsigned short* dst = vt + ((size_t)bh * 64 + d) * 2048 + t0;
#pragma unroll
  for (int tb2 = 0; tb2 < 2; ++tb2) {
    int tb = (tid & 3) * 2 + tb2;
    union { unsigned short s[8]; bf16x8 v; } o;
#pragma unroll
    for (int i = 0; i < 8; ++i) {
      int row = tb * 8 + i;
      o.s[i] = Ts[row][(((d >> 3) ^ (row & 7)) * 8) + (d & 7)];
    }
    *(bf16x8*)(dst + tb * 8) = o.v;
  }
}

// ---------------------------------------------------------------------------
// Big GEMM template: C[M,N] = A[M,1024] * B[N,1024]^T.
// 256x128 tile, 8 waves (4Mx2N), BK=64, mfma_32x32x16, counted-vmcnt loop.
// ---------------------------------------------------------------------------
template <int N, int OUT_BF16>
__global__ __launch_bounds__(512)
void gemm_big(const unsigned short* __restrict__ A,
              const unsigned short* __restrict__ B,
              void* __restrict__ Cout) {
  const int K = 1024;
  __shared__ __align__(16) unsigned short As[2][2][128 * 64];
  __shared__ __align__(16) unsigned short Bs[2][128 * 64];

  const int tid = threadIdx.x, wid = tid >> 6, lane = tid & 63;
  const int l31 = lane & 31, h = lane >> 5;
  const int NBX = N / 128;
  const int nwg8 = (int)gridDim.x >> 3;
  const int wgid = ((int)blockIdx.x & 7) * nwg8 + ((int)blockIdx.x >> 3);
  const int bx = wgid % NBX, by = wgid / NBX;
  const int m0 = by * 256, n0 = bx * 128;
  const int wr = wid >> 1, wc = wid & 1;

  auto stage = [&](int t, int buf) {
    const int k0 = t * 64;
    const int r8 = lane >> 3;
    const int blk = (lane & 7) ^ r8;
#pragma unroll
    for (int hh = 0; hh < 2; ++hh)
#pragma unroll
      for (int r = 0; r < 2; ++r) {
        int row = r * 64 + wid * 8 + r8;
        gload_lds16(A + (size_t)(m0 + hh * 128 + row) * K + k0 + blk * 8,
                    &As[buf][hh][r * 4096 + wid * 512]);
      }
#pragma unroll
    for (int r = 0; r < 2; ++r) {
      int row = r * 64 + wid * 8 + r8;
      gload_lds16(B + (size_t)(n0 + row) * K + k0 + blk * 8,
                  &Bs[buf][r * 4096 + wid * 512]);
    }
  };

  f32x16 acc[2][2] = {};

  stage(0, 0);

  int cur = 0;
  for (int t = 0; t < 16; ++t) {
    __builtin_amdgcn_s_barrier();
    if (t + 1 < 16) {
      stage(t + 1, cur ^ 1);
      asm volatile("s_waitcnt vmcnt(6)" ::: "memory");
    } else {
      asm volatile("s_waitcnt vmcnt(0)" ::: "memory");
    }
    __builtin_amdgcn_s_barrier();
    __builtin_amdgcn_sched_barrier(0);

    bf16x8 af[2][4], bfr[2][4];
#pragma unroll
    for (int mi = 0; mi < 2; ++mi) {
      int row = (wr & 1) * 64 + mi * 32 + l31;
#pragma unroll
      for (int ks = 0; ks < 4; ++ks) {
        int chunk = (ks * 2 + h) ^ (row & 7);
        af[mi][ks] = *(const bf16x8*)&As[cur][wr >> 1][row * 64 + chunk * 8];
      }
    }
#pragma unroll
    for (int ni = 0; ni < 2; ++ni) {
      int row = wc * 64 + ni * 32 + l31;
#pragma unroll
      for (int ks = 0; ks < 4; ++ks) {
        int chunk = (ks * 2 + h) ^ (row & 7);
        bfr[ni][ks] = *(const bf16x8*)&Bs[cur][row * 64 + chunk * 8];
      }
    }
    __builtin_amdgcn_s_setprio(1);
#pragma unroll
    for (int ks = 0; ks < 4; ++ks)
#pragma unroll
      for (int mi = 0; mi < 2; ++mi)
#pragma unroll
        for (int ni = 0; ni < 2; ++ni)
          acc[mi][ni] = __builtin_amdgcn_mfma_f32_32x32x16_bf16(
              af[mi][ks], bfr[ni][ks], acc[mi][ni], 0, 0, 0);
    __builtin_amdgcn_s_setprio(0);
    cur ^= 1;
  }

#pragma unroll
  for (int mi = 0; mi < 2; ++mi)
#pragma unroll
    for (int ni = 0; ni < 2; ++ni)
#pragma unroll
      for (int reg = 0; reg < 16; ++reg) {
        int row = m0 + wr * 64 + mi * 32 + (reg & 3) + 8 * (reg >> 2) + 4 * h;
        int col = n0 + wc * 64 + ni * 32 + l31;
        if (OUT_BF16)
          ((unsigned short*)Cout)[(size_t)row * N + col] =
              f2b_rne(acc[mi][ni][reg]);
        else
          ((float*)Cout)[(size_t)row * N + col] = acc[mi][ni][reg];
      }
}

// ---------------------------------------------------------------------------
// Flash attention fwd, causal; swapped-QK^T 32x32; 64 q-rows per wave
// (two 32-row halves sharing each staged K tile).  Static XCD map (R12).
// VGPR 124 under launch_bounds(256,2) -> 2 blocks/CU residency (critical).
// ---------------------------------------------------------------------------
__global__ __launch_bounds__(256, 2)
void attn_fwd(const unsigned short* __restrict__ qkv,
              const unsigned short* __restrict__ vt,
              unsigned short* __restrict__ out) {
  const int T = 2048, C3 = 3072;
  __shared__ __align__(16) unsigned short Ks[2][64][64];  // [kv][d] swizzled
  __shared__ __align__(16) unsigned short Vs[2][64][64];  // [d][kv] swizzled
  __shared__ float Bc[4][32];                             // per-wave broadcast

  const int tid = threadIdx.x, w = tid >> 6, lane = tid & 63;
  const int l31 = lane & 31, h = lane >> 5;
  const int wgid = (blockIdx.x & 7) * 64 + (blockIdx.x >> 3);
  const int local = wgid & 63, xcd = wgid >> 6;
  const int qidx = local >> 3, bhl = local & 7;
  const int bh = xcd * 8 + bhl;
  const int qt = (qidx < 4) ? (7 - qidx) : (qidx - 4);
  const int b = bh >> 4, hed = bh & 15;
  const int qw = qt * 256 + w * 64;
  const size_t rowbase = (size_t)b * T * C3;
  const int hoff = hed * 64;
  const unsigned short* vbase = vt + (size_t)bh * 64 * 2048;
  const float c2 = 0.18033688f;  // 0.125 * log2(e)

  auto stageK = [&](int kv0, int buf) {
#pragma unroll
    for (int pp = 0; pp < 2; ++pp) {
      int chunk = w * 2 + pp;
      int row = chunk * 8 + (lane >> 3);
      int blk = (lane & 7) ^ (lane >> 3);
      gload_lds16(
          qkv + rowbase + (size_t)(kv0 + row) * C3 + 1024 + hoff + blk * 8,
          &Ks[buf][chunk * 8][0]);
    }
  };
  auto stageV = [&](int kv0, int buf) {
#pragma unroll
    for (int pp = 0; pp < 2; ++pp) {
      int chunk = w * 2 + pp;
      int drow = chunk * 8 + (lane >> 3);
      int blk = (lane & 7) ^ (lane >> 3);
      gload_lds16(vbase + (size_t)drow * 2048 + kv0 + blk * 8,
                  &Vs[buf][chunk * 8][0]);
    }
  };

  bf16x8 qf0[4], qf1[4];
  {
    const unsigned short* qp0 =
        qkv + rowbase + (size_t)(qw + l31) * C3 + hoff + h * 8;
    const unsigned short* qp1 = qp0 + 32 * C3;
#pragma unroll
    for (int s = 0; s < 4; ++s) {
      qf0[s] = *(const bf16x8*)(qp0 + 16 * s);
      qf1[s] = *(const bf16x8*)(qp1 + 16 * s);
    }
  }

  f32x16 oacc0[2] = {}, oacc1[2] = {};
  float mr0 = -1e30f, mr1 = -1e30f, sum0 = 0.f, sum1 = 0.f;

  stageK(0, 0);
  stageV(0, 0);

  auto do_half = [&](f32x16 (&sacc)[2], int qx, float& mr, float& sm,
                     f32x16 (&oc)[2], int t, int kv0, int cur) {
    if (kv0 + 64 > qx) {
      int q_abs = qx + l31;
#pragma unroll
      for (int kt = 0; kt < 2; ++kt)
#pragma unroll
        for (int r = 0; r < 16; ++r) {
          int kv_abs = kv0 + kt * 32 + (r & 3) + 8 * (r >> 2) + 4 * h;
          if (kv_abs > q_abs) sacc[kt][r] = -1e30f;
        }
    }
    float mx[8];
#pragma unroll
    for (int g = 0; g < 8; ++g)
      mx[g] = fmaxf(fmaxf(sacc[g >> 2][(g & 3) * 4 + 0],
                          sacc[g >> 2][(g & 3) * 4 + 1]),
                    fmaxf(sacc[g >> 2][(g & 3) * 4 + 2],
                          sacc[g >> 2][(g & 3) * 4 + 3]));
    float tm = fmaxf(fmaxf(fmaxf(mx[0], mx[1]), fmaxf(mx[2], mx[3])),
                     fmaxf(fmaxf(mx[4], mx[5]), fmaxf(mx[6], mx[7])));
    tm = fmaxf(tm, __shfl_xor(tm, 32));
    if (t == 0) {
      mr = tm;
    } else if (!__all(tm <= mr + 16.0f)) {
      float mnew = fmaxf(mr, tm);
      float corr = __builtin_amdgcn_exp2f((mr - mnew) * c2);
      sm *= corr;
      if (h == 0) Bc[w][l31] = corr;
      mr = mnew;
      asm volatile("s_waitcnt lgkmcnt(0)" ::: "memory");
#pragma unroll
      for (int r = 0; r < 16; ++r) {
        float cr = Bc[w][(r & 3) + 8 * (r >> 2) + 4 * h];
        oc[0][r] *= cr;
        oc[1][r] *= cr;
      }
    }
    float m2 = mr * c2;
    float s0 = 0.f, s1 = 0.f, s2 = 0.f, s3 = 0.f;
#pragma unroll
    for (int kt = 0; kt < 2; ++kt)
#pragma unroll
      for (int r = 0; r < 16; r += 4) {
        float p0 = __builtin_amdgcn_exp2f(fmaf(sacc[kt][r + 0], c2, -m2));
        float p1 = __builtin_amdgcn_exp2f(fmaf(sacc[kt][r + 1], c2, -m2));
        float p2 = __builtin_amdgcn_exp2f(fmaf(sacc[kt][r + 2], c2, -m2));
        float p3 = __builtin_amdgcn_exp2f(fmaf(sacc[kt][r + 3], c2, -m2));
        sacc[kt][r + 0] = p0; sacc[kt][r + 1] = p1;
        sacc[kt][r + 2] = p2; sacc[kt][r + 3] = p3;
        s0 += p0; s1 += p1; s2 += p2; s3 += p3;
      }
    float sl = (s0 + s1) + (s2 + s3);
    sm += sl + __shfl_xor(sl, 32);
    unsigned pk[16];
#pragma unroll
    for (int kt = 0; kt < 2; ++kt)
#pragma unroll
      for (int r = 0; r < 16; r += 2)
        pk[kt * 8 + (r >> 1)] = cvt_pk_bf16(sacc[kt][r], sacc[kt][r + 1]);
    __builtin_amdgcn_s_setprio(1);
#pragma unroll
    for (int sg = 0; sg < 4; ++sg) {
      const int kt = sg >> 1, s = sg & 1;
      const int base = kt * 8 + 4 * s;
      uint2v r02 = __builtin_amdgcn_permlane32_swap(pk[base], pk[base + 2],
                                                    false, false);
      uint2v r13 = __builtin_amdgcn_permlane32_swap(pk[base + 1], pk[base + 3],
                                                    false, false);
      union { unsigned u[4]; bf16x8 v; } Afr;
      Afr.u[0] = r02.x; Afr.u[1] = r13.x;
      Afr.u[2] = r02.y; Afr.u[3] = r13.y;
#pragma unroll
      for (int dt = 0; dt < 2; ++dt) {
        int d = dt * 32 + l31;
        int blk = (2 * sg + h) ^ (d & 7);
        bf16x8 vf = *(const bf16x8*)&Vs[cur][d][blk * 8];
        oc[dt] = __builtin_amdgcn_mfma_f32_32x32x16_bf16(Afr.v, vf,
                                                         oc[dt], 0, 0, 0);
      }
    }
    __builtin_amdgcn_s_setprio(0);
  };

  int cur = 0;
  const int ntiles = 4 * qt + 4;
  for (int t = 0; t < ntiles; ++t) {
    const int kv0 = t * 64;
    __builtin_amdgcn_s_barrier();
    if (t + 1 < ntiles) {
      stageK(kv0 + 64, cur ^ 1);
      stageV(kv0 + 64, cur ^ 1);
      asm volatile("s_waitcnt vmcnt(4)" ::: "memory");
    } else {
      asm volatile("s_waitcnt vmcnt(0)" ::: "memory");
    }
    __builtin_amdgcn_s_barrier();
    __builtin_amdgcn_sched_barrier(0);

    if (kv0 <= qw) {
      f32x16 sacc0[2] = {}, sacc1[2] = {};
      __builtin_amdgcn_s_setprio(1);
#pragma unroll
      for (int s = 0; s < 4; ++s) {
#pragma unroll
        for (int kt = 0; kt < 2; ++kt) {
          int row = kt * 32 + l31;
          int blk = (2 * s + h) ^ (row & 7);
          bf16x8 kf = *(const bf16x8*)&Ks[cur][row][blk * 8];
          sacc0[kt] = __builtin_amdgcn_mfma_f32_32x32x16_bf16(kf, qf0[s],
                                                              sacc0[kt], 0, 0, 0);
          sacc1[kt] = __builtin_amdgcn_mfma_f32_32x32x16_bf16(kf, qf1[s],
                                                              sacc1[kt], 0, 0, 0);
        }
      }
      __builtin_amdgcn_s_setprio(0);
      do_half(sacc0, qw, mr0, sum0, oacc0, t, kv0, cur);
      do_half(sacc1, qw + 32, mr1, sum1, oacc1, t, kv0, cur);
    }
    cur ^= 1;
  }

#pragma unroll
  for (int X = 0; X < 2; ++X) {
    float sm = X ? sum1 : sum0;
    if (h == 0) Bc[w][l31] = 1.0f / sm;
    asm volatile("s_waitcnt lgkmcnt(0)" ::: "memory");
#pragma unroll
    for (int r = 0; r < 16; ++r) {
      int ql = (r & 3) + 8 * (r >> 2) + 4 * h;
      float inv = Bc[w][ql];
      int q_abs = qw + 32 * X + ql;
#pragma unroll
      for (int dt = 0; dt < 2; ++dt) {
        float v = (X ? oacc1 : oacc0)[dt][r] * inv;
        out[(size_t)(b * T + q_abs) * 1024 + hoff + dt * 32 + l31] =
            f2b_rne(v);
      }
    }
    __builtin_amdgcn_s_barrier();  // Bc reuse between halves
  }
}

// ---------------------------------------------------------------------------
extern "C" void kernel_launch(void* const* d_in, const int* in_sizes, int n_in,
                              void* d_out, int out_size, void* d_ws,
                              size_t ws_size, hipStream_t stream) {
  const float* x = (const float*)d_in[0];      // [4,2048,1024]
  const float* w_qkv = (const float*)d_in[1];  // [3072,1024]
  const float* w_out = (const float*)d_in[2];  // [1024,1024]
  float* out = (float*)d_out;                  // [4,2048,1024] fp32

  const int M = 8192, C = 1024, C3 = 3072;

  unsigned short* xb = (unsigned short*)d_ws;      // M*C  (reused as attno)
  unsigned short* wqkvb = xb + (size_t)M * C;      // C3*C
  unsigned short* woutb = wqkvb + (size_t)C3 * C;  // C*C
  unsigned short* qkv = woutb + (size_t)C * C;     // M*C3
  unsigned short* vtb = qkv + (size_t)M * C3;      // B*H*64*T = M*C
  unsigned short* attno = xb;                      // alias: xb dead post-GEMM1

  fused_convert<<<2048, 256, 0, stream>>>(x, w_qkv, w_out, xb, wqkvb, woutb);

  gemm_big<3072, 1><<<768, 512, 0, stream>>>(xb, wqkvb, qkv);

  v_transpose<<<dim3(32, 64), 256, 0, stream>>>(qkv, vtb);

  attn_fwd<<<512, 256, 0, stream>>>(qkv, vtb, attno);

  gemm_big<1024, 0><<<256, 512, 0, stream>>>(attno, woutb, out);
}

// Round 18
// 182.405 us; speedup vs baseline: 1.1871x; 1.0217x over previous
//
#include <hip/hip_runtime.h>
#include <hip/hip_bf16.h>

// ---------------------------------------------------------------------------
// Fused causal MHA forward: x[B,T,C] fp32, w_qkv[3C,C] fp32, w_out[C,C] fp32
// B=4 T=2048 C=1024 H=16 hd=64.  All matmuls in bf16 MFMA, fp32 accumulate.
// fused convert | GEMM qkv | V-transpose | flash-attn (static map) | proj.
// R17: attn super-tiles 128 kv per barrier-pair (2x64 compute passes),
// halving barrier count; 8 loads in flight; wave-private Bc (no epi barrier).
// ---------------------------------------------------------------------------

typedef __attribute__((ext_vector_type(8))) short bf16x8;
typedef __attribute__((ext_vector_type(4))) float f32x4;
typedef __attribute__((ext_vector_type(16))) float f32x16;
typedef __attribute__((ext_vector_type(2))) unsigned uint2v;

#define GLOBAL_AS __attribute__((address_space(1)))
#define LDS_AS __attribute__((address_space(3)))

__device__ __forceinline__ unsigned short f2b_rne(float f) {
  unsigned u = __float_as_uint(f);
  unsigned r = u + 0x7fffu + ((u >> 16) & 1u);
  return (unsigned short)(r >> 16);
}

__device__ __forceinline__ unsigned cvt_pk_bf16(float lo, float hi) {
  unsigned r;
  asm("v_cvt_pk_bf16_f32 %0, %1, %2" : "=v"(r) : "v"(lo), "v"(hi));
  return r;
}

__device__ __forceinline__ void gload_lds16(const void* g, void* l) {
  __builtin_amdgcn_global_load_lds((const GLOBAL_AS void*)g, (LDS_AS void*)l, 16, 0, 0);
}

// ---------------------------------------------------------------------------
// Fused fp32 -> bf16 conversion of all three inputs.
// ---------------------------------------------------------------------------
__global__ void fused_convert(const float* __restrict__ x,
                              const float* __restrict__ wqkv,
                              const float* __restrict__ wout,
                              unsigned short* __restrict__ xb,
                              unsigned short* __restrict__ wqkvb,
                              unsigned short* __restrict__ woutb) {
  const int nx = 8192 * 1024 / 4, nq = 3072 * 1024 / 4, nw = 1024 * 1024 / 4;
  const int ntot = nx + nq + nw;
  int i = blockIdx.x * blockDim.x + threadIdx.x;
  int stride = gridDim.x * blockDim.x;
  for (; i < ntot; i += stride) {
    const float* src;
    unsigned short* dst;
    int j = i;
    if (j < nx) {
      src = x; dst = xb;
    } else if ((j -= nx) < nq) {
      src = wqkv; dst = wqkvb;
    } else {
      j -= nq; src = wout; dst = woutb;
    }
    float4 v = reinterpret_cast<const float4*>(src)[j];
    ushort4 o;
    o.x = f2b_rne(v.x); o.y = f2b_rne(v.y);
    o.z = f2b_rne(v.z); o.w = f2b_rne(v.w);
    reinterpret_cast<ushort4*>(dst)[j] = o;
  }
}

// ---------------------------------------------------------------------------
// V transpose: qkv V-block rows -> vt[bh][d][T] via swizzled 64x64 LDS tile.
// ---------------------------------------------------------------------------
__global__ __launch_bounds__(256)
void v_transpose(const unsigned short* __restrict__ qkv,
                 unsigned short* __restrict__ vt) {
  __shared__ __align__(16) unsigned short Ts[64][64];
  const int tc = blockIdx.x, bh = blockIdx.y;
  const int b = bh >> 4, hed = bh & 15;
  const int t0 = tc * 64;
  const int tid = threadIdx.x;
  {
    const int r = tid >> 2, cb = (tid & 3) * 2;
    const unsigned short* src =
        qkv + (size_t)(b * 2048 + t0 + r) * 3072 + 2048 + hed * 64;
    bf16x8 v0 = *(const bf16x8*)(src + cb * 8);
    bf16x8 v1 = *(const bf16x8*)(src + cb * 8 + 8);
    *(bf16x8*)&Ts[r][(cb ^ (r & 7)) * 8] = v0;
    *(bf16x8*)&Ts[r][((cb + 1) ^ (r & 7)) * 8] = v1;
  }
  __syncthreads();
  const int d = tid >> 2;
  unsigned short* dst = vt + ((size_t)bh * 64 + d) * 2048 + t0;
#pragma unroll
  for (int tb2 = 0; tb2 < 2; ++tb2) {
    int tb = (tid & 3) * 2 + tb2;
    union { unsigned short s[8]; bf16x8 v; } o;
#pragma unroll
    for (int i = 0; i < 8; ++i) {
      int row = tb * 8 + i;
      o.s[i] = Ts[row][(((d >> 3) ^ (row & 7)) * 8) + (d & 7)];
    }
    *(bf16x8*)(dst + tb * 8) = o.v;
  }
}

// ---------------------------------------------------------------------------
// Big GEMM template: C[M,N] = A[M,1024] * B[N,1024]^T.
// 256x128 tile, 8 waves (4Mx2N), BK=64, mfma_32x32x16, counted-vmcnt loop.
// ---------------------------------------------------------------------------
template <int N, int OUT_BF16>
__global__ __launch_bounds__(512)
void gemm_big(const unsigned short* __restrict__ A,
              const unsigned short* __restrict__ B,
              void* __restrict__ Cout) {
  const int K = 1024;
  __shared__ __align__(16) unsigned short As[2][2][128 * 64];
  __shared__ __align__(16) unsigned short Bs[2][128 * 64];

  const int tid = threadIdx.x, wid = tid >> 6, lane = tid & 63;
  const int l31 = lane & 31, h = lane >> 5;
  const int NBX = N / 128;
  const int nwg8 = (int)gridDim.x >> 3;
  const int wgid = ((int)blockIdx.x & 7) * nwg8 + ((int)blockIdx.x >> 3);
  const int bx = wgid % NBX, by = wgid / NBX;
  const int m0 = by * 256, n0 = bx * 128;
  const int wr = wid >> 1, wc = wid & 1;

  auto stage = [&](int t, int buf) {
    const int k0 = t * 64;
    const int r8 = lane >> 3;
    const int blk = (lane & 7) ^ r8;
#pragma unroll
    for (int hh = 0; hh < 2; ++hh)
#pragma unroll
      for (int r = 0; r < 2; ++r) {
        int row = r * 64 + wid * 8 + r8;
        gload_lds16(A + (size_t)(m0 + hh * 128 + row) * K + k0 + blk * 8,
                    &As[buf][hh][r * 4096 + wid * 512]);
      }
#pragma unroll
    for (int r = 0; r < 2; ++r) {
      int row = r * 64 + wid * 8 + r8;
      gload_lds16(B + (size_t)(n0 + row) * K + k0 + blk * 8,
                  &Bs[buf][r * 4096 + wid * 512]);
    }
  };

  f32x16 acc[2][2] = {};

  stage(0, 0);

  int cur = 0;
  for (int t = 0; t < 16; ++t) {
    __builtin_amdgcn_s_barrier();
    if (t + 1 < 16) {
      stage(t + 1, cur ^ 1);
      asm volatile("s_waitcnt vmcnt(6)" ::: "memory");
    } else {
      asm volatile("s_waitcnt vmcnt(0)" ::: "memory");
    }
    __builtin_amdgcn_s_barrier();
    __builtin_amdgcn_sched_barrier(0);

    bf16x8 af[2][4], bfr[2][4];
#pragma unroll
    for (int mi = 0; mi < 2; ++mi) {
      int row = (wr & 1) * 64 + mi * 32 + l31;
#pragma unroll
      for (int ks = 0; ks < 4; ++ks) {
        int chunk = (ks * 2 + h) ^ (row & 7);
        af[mi][ks] = *(const bf16x8*)&As[cur][wr >> 1][row * 64 + chunk * 8];
      }
    }
#pragma unroll
    for (int ni = 0; ni < 2; ++ni) {
      int row = wc * 64 + ni * 32 + l31;
#pragma unroll
      for (int ks = 0; ks < 4; ++ks) {
        int chunk = (ks * 2 + h) ^ (row & 7);
        bfr[ni][ks] = *(const bf16x8*)&Bs[cur][row * 64 + chunk * 8];
      }
    }
    __builtin_amdgcn_s_setprio(1);
#pragma unroll
    for (int ks = 0; ks < 4; ++ks)
#pragma unroll
      for (int mi = 0; mi < 2; ++mi)
#pragma unroll
        for (int ni = 0; ni < 2; ++ni)
          acc[mi][ni] = __builtin_amdgcn_mfma_f32_32x32x16_bf16(
              af[mi][ks], bfr[ni][ks], acc[mi][ni], 0, 0, 0);
    __builtin_amdgcn_s_setprio(0);
    cur ^= 1;
  }

#pragma unroll
  for (int mi = 0; mi < 2; ++mi)
#pragma unroll
    for (int ni = 0; ni < 2; ++ni)
#pragma unroll
      for (int reg = 0; reg < 16; ++reg) {
        int row = m0 + wr * 64 + mi * 32 + (reg & 3) + 8 * (reg >> 2) + 4 * h;
        int col = n0 + wc * 64 + ni * 32 + l31;
        if (OUT_BF16)
          ((unsigned short*)Cout)[(size_t)row * N + col] =
              f2b_rne(acc[mi][ni][reg]);
        else
          ((float*)Cout)[(size_t)row * N + col] = acc[mi][ni][reg];
      }
}

// ---------------------------------------------------------------------------
// Flash attention fwd, causal; swapped-QK^T 32x32; 64 q-rows per wave.
// Super-tile staging: 128 kv rows per barrier-pair, computed as two
// sequential 64-row passes (state reused; VGPR unchanged).  Static XCD map.
// ---------------------------------------------------------------------------
__global__ __launch_bounds__(256, 2)
void attn_fwd(const unsigned short* __restrict__ qkv,
              const unsigned short* __restrict__ vt,
              unsigned short* __restrict__ out) {
  const int T = 2048, C3 = 3072;
  __shared__ __align__(16) unsigned short Ks[2][128][64];  // [kv][d] swizzled
  __shared__ __align__(16) unsigned short Vs[2][64][128];  // [d][kv] swizzled
  __shared__ float Bc[4][32];  // per-wave broadcast (wave-private)

  const int tid = threadIdx.x, w = tid >> 6, lane = tid & 63;
  const int l31 = lane & 31, h = lane >> 5;
  const int wgid = (blockIdx.x & 7) * 64 + (blockIdx.x >> 3);
  const int local = wgid & 63, xcd = wgid >> 6;
  const int qidx = local >> 3, bhl = local & 7;
  const int bh = xcd * 8 + bhl;
  const int qt = (qidx < 4) ? (7 - qidx) : (qidx - 4);
  const int b = bh >> 4, hed = bh & 15;
  const int qw = qt * 256 + w * 64;
  const size_t rowbase = (size_t)b * T * C3;
  const int hoff = hed * 64;
  const unsigned short* vbase = vt + (size_t)bh * 64 * 2048;
  const float c2 = 0.18033688f;  // 0.125 * log2(e)

  // stage 128 kv rows of K: 16 chunks of 8 rows, 4 per wave.
  auto stageK = [&](int kv0, int buf) {
#pragma unroll
    for (int pp = 0; pp < 4; ++pp) {
      int chunk = w * 4 + pp;
      int row = chunk * 8 + (lane >> 3);
      int blk = (lane & 7) ^ (lane >> 3);  // (lane&7) ^ (row&7)
      gload_lds16(
          qkv + rowbase + (size_t)(kv0 + row) * C3 + 1024 + hoff + blk * 8,
          &Ks[buf][chunk * 8][0]);
    }
  };
  // stage 128 kv cols of V^T rows: 16 chunks of 4 d-rows (256B each), 4/wave.
  // Stored kv-block at row d, position pos is (pos&8)|((pos&7)^(d&7)) so the
  // read  Vs[d][p*64 + ((2sg+h)^(d&7))*8]  yields kv block p*8 + (2sg+h).
  auto stageV = [&](int kv0, int buf) {
#pragma unroll
    for (int pp = 0; pp < 4; ++pp) {
      int c = w * 4 + pp;
      int d = c * 4 + (lane >> 4);
      int pos = lane & 15;
      int kvb = (pos & 8) | ((pos & 7) ^ (d & 7));
      gload_lds16(vbase + (size_t)d * 2048 + kv0 + kvb * 8,
                  &Vs[buf][c * 4][0]);
    }
  };

  bf16x8 qf0[4], qf1[4];
  {
    const unsigned short* qp0 =
        qkv + rowbase + (size_t)(qw + l31) * C3 + hoff + h * 8;
    const unsigned short* qp1 = qp0 + 32 * C3;
#pragma unroll
    for (int s = 0; s < 4; ++s) {
      qf0[s] = *(const bf16x8*)(qp0 + 16 * s);
      qf1[s] = *(const bf16x8*)(qp1 + 16 * s);
    }
  }

  f32x16 oacc0[2] = {}, oacc1[2] = {};
  float mr0 = -1e30f, mr1 = -1e30f, sum0 = 0.f, sum1 = 0.f;

  stageK(0, 0);
  stageV(0, 0);

  // softmax + PV for one 32-row half at kv offset kvp (pass p -> vofs=p*64).
  auto do_half = [&](f32x16 (&sacc)[2], int qx, float& mr, float& sm,
                     f32x16 (&oc)[2], bool first, int kvp, int cur, int vofs) {
    if (kvp + 64 > qx) {
      int q_abs = qx + l31;
#pragma unroll
      for (int kt = 0; kt < 2; ++kt)
#pragma unroll
        for (int r = 0; r < 16; ++r) {
          int kv_abs = kvp + kt * 32 + (r & 3) + 8 * (r >> 2) + 4 * h;
          if (kv_abs > q_abs) sacc[kt][r] = -1e30f;
        }
    }
    float mx[8];
#pragma unroll
    for (int g = 0; g < 8; ++g)
      mx[g] = fmaxf(fmaxf(sacc[g >> 2][(g & 3) * 4 + 0],
                          sacc[g >> 2][(g & 3) * 4 + 1]),
                    fmaxf(sacc[g >> 2][(g & 3) * 4 + 2],
                          sacc[g >> 2][(g & 3) * 4 + 3]));
    float tm = fmaxf(fmaxf(fmaxf(mx[0], mx[1]), fmaxf(mx[2], mx[3])),
                     fmaxf(fmaxf(mx[4], mx[5]), fmaxf(mx[6], mx[7])));
    tm = fmaxf(tm, __shfl_xor(tm, 32));
    if (first) {
      mr = tm;
    } else if (!__all(tm <= mr + 16.0f)) {
      float mnew = fmaxf(mr, tm);
      float corr = __builtin_amdgcn_exp2f((mr - mnew) * c2);
      sm *= corr;
      if (h == 0) Bc[w][l31] = corr;
      mr = mnew;
      asm volatile("s_waitcnt lgkmcnt(0)" ::: "memory");
#pragma unroll
      for (int r = 0; r < 16; ++r) {
        float cr = Bc[w][(r & 3) + 8 * (r >> 2) + 4 * h];
        oc[0][r] *= cr;
        oc[1][r] *= cr;
      }
    }
    float m2 = mr * c2;
    float s0 = 0.f, s1 = 0.f, s2 = 0.f, s3 = 0.f;
#pragma unroll
    for (int kt = 0; kt < 2; ++kt)
#pragma unroll
      for (int r = 0; r < 16; r += 4) {
        float p0 = __builtin_amdgcn_exp2f(fmaf(sacc[kt][r + 0], c2, -m2));
        float p1 = __builtin_amdgcn_exp2f(fmaf(sacc[kt][r + 1], c2, -m2));
        float p2 = __builtin_amdgcn_exp2f(fmaf(sacc[kt][r + 2], c2, -m2));
        float p3 = __builtin_amdgcn_exp2f(fmaf(sacc[kt][r + 3], c2, -m2));
        sacc[kt][r + 0] = p0; sacc[kt][r + 1] = p1;
        sacc[kt][r + 2] = p2; sacc[kt][r + 3] = p3;
        s0 += p0; s1 += p1; s2 += p2; s3 += p3;
      }
    float sl = (s0 + s1) + (s2 + s3);
    sm += sl + __shfl_xor(sl, 32);
    unsigned pk[16];
#pragma unroll
    for (int kt = 0; kt < 2; ++kt)
#pragma unroll
      for (int r = 0; r < 16; r += 2)
        pk[kt * 8 + (r >> 1)] = cvt_pk_bf16(sacc[kt][r], sacc[kt][r + 1]);
    __builtin_amdgcn_s_setprio(1);
#pragma unroll
    for (int sg = 0; sg < 4; ++sg) {
      const int kt = sg >> 1, s = sg & 1;
      const int base = kt * 8 + 4 * s;
      uint2v r02 = __builtin_amdgcn_permlane32_swap(pk[base], pk[base + 2],
                                                    false, false);
      uint2v r13 = __builtin_amdgcn_permlane32_swap(pk[base + 1], pk[base + 3],
                                                    false, false);
      union { unsigned u[4]; bf16x8 v; } Afr;
      Afr.u[0] = r02.x; Afr.u[1] = r13.x;
      Afr.u[2] = r02.y; Afr.u[3] = r13.y;
#pragma unroll
      for (int dt = 0; dt < 2; ++dt) {
        int d = dt * 32 + l31;
        int blk = (2 * sg + h) ^ (d & 7);
        bf16x8 vf = *(const bf16x8*)&Vs[cur][d][vofs + blk * 8];
        oc[dt] = __builtin_amdgcn_mfma_f32_32x32x16_bf16(Afr.v, vf,
                                                         oc[dt], 0, 0, 0);
      }
    }
    __builtin_amdgcn_s_setprio(0);
  };

  int cur = 0;
  const int nsup = 2 * qt + 2;  // super-tiles of 128 kv
  for (int t = 0; t < nsup; ++t) {
    const int kv0 = t * 128;
    __builtin_amdgcn_s_barrier();
    if (t + 1 < nsup) {
      stageK(kv0 + 128, cur ^ 1);
      stageV(kv0 + 128, cur ^ 1);
      asm volatile("s_waitcnt vmcnt(8)" ::: "memory");  // waits tile t's loads
    } else {
      asm volatile("s_waitcnt vmcnt(0)" ::: "memory");
    }
    __builtin_amdgcn_s_barrier();
    __builtin_amdgcn_sched_barrier(0);

#pragma unroll
    for (int p = 0; p < 2; ++p) {
      const int kvp = kv0 + p * 64;
      if (kvp <= qw) {
        f32x16 sacc0[2] = {}, sacc1[2] = {};
        __builtin_amdgcn_s_setprio(1);
#pragma unroll
        for (int s = 0; s < 4; ++s) {
#pragma unroll
          for (int kt = 0; kt < 2; ++kt) {
            int row = kt * 32 + l31;
            int blk = (2 * s + h) ^ (row & 7);
            bf16x8 kf = *(const bf16x8*)&Ks[cur][p * 64 + row][blk * 8];
            sacc0[kt] = __builtin_amdgcn_mfma_f32_32x32x16_bf16(
                kf, qf0[s], sacc0[kt], 0, 0, 0);
            sacc1[kt] = __builtin_amdgcn_mfma_f32_32x32x16_bf16(
                kf, qf1[s], sacc1[kt], 0, 0, 0);
          }
        }
        __builtin_amdgcn_s_setprio(0);
        const bool first = (t == 0 && p == 0);
        do_half(sacc0, qw, mr0, sum0, oacc0, first, kvp, cur, p * 64);
        do_half(sacc1, qw + 32, mr1, sum1, oacc1, first, kvp, cur, p * 64);
      }
    }
    cur ^= 1;
  }

  // epilogue (Bc is wave-private: lgkmcnt suffices, no barriers)
#pragma unroll
  for (int X = 0; X < 2; ++X) {
    float sm = X ? sum1 : sum0;
    if (h == 0) Bc[w][l31] = 1.0f / sm;
    asm volatile("s_waitcnt lgkmcnt(0)" ::: "memory");
#pragma unroll
    for (int r = 0; r < 16; ++r) {
      int ql = (r & 3) + 8 * (r >> 2) + 4 * h;
      float inv = Bc[w][ql];
      int q_abs = qw + 32 * X + ql;
#pragma unroll
      for (int dt = 0; dt < 2; ++dt) {
        float v = (X ? oacc1 : oacc0)[dt][r] * inv;
        out[(size_t)(b * T + q_abs) * 1024 + hoff + dt * 32 + l31] =
            f2b_rne(v);
      }
    }
  }
}

// ---------------------------------------------------------------------------
extern "C" void kernel_launch(void* const* d_in, const int* in_sizes, int n_in,
                              void* d_out, int out_size, void* d_ws,
                              size_t ws_size, hipStream_t stream) {
  const float* x = (const float*)d_in[0];      // [4,2048,1024]
  const float* w_qkv = (const float*)d_in[1];  // [3072,1024]
  const float* w_out = (const float*)d_in[2];  // [1024,1024]
  float* out = (float*)d_out;                  // [4,2048,1024] fp32

  const int M = 8192, C = 1024, C3 = 3072;

  unsigned short* xb = (unsigned short*)d_ws;      // M*C  (reused as attno)
  unsigned short* wqkvb = xb + (size_t)M * C;      // C3*C
  unsigned short* woutb = wqkvb + (size_t)C3 * C;  // C*C
  unsigned short* qkv = woutb + (size_t)C * C;     // M*C3
  unsigned short* vtb = qkv + (size_t)M * C3;      // B*H*64*T = M*C
  unsigned short* attno = xb;                      // alias: xb dead post-GEMM1

  fused_convert<<<2048, 256, 0, stream>>>(x, w_qkv, w_out, xb, wqkvb, woutb);

  gemm_big<3072, 1><<<768, 512, 0, stream>>>(xb, wqkvb, qkv);

  v_transpose<<<dim3(32, 64), 256, 0, stream>>>(qkv, vtb);

  attn_fwd<<<512, 256, 0, stream>>>(qkv, vtb, attno);

  gemm_big<1024, 0><<<256, 512, 0, stream>>>(attno, woutb, out);
}

// Round 19
// 176.324 us; speedup vs baseline: 1.2281x; 1.0345x over previous
//
#include <hip/hip_runtime.h>
#include <hip/hip_bf16.h>

// ---------------------------------------------------------------------------
// Fused causal MHA forward: x[B,T,C] fp32, w_qkv[3C,C] fp32, w_out[C,C] fp32
// B=4 T=2048 C=1024 H=16 hd=64.  All matmuls in bf16 MFMA, fp32 accumulate.
// fused convert | GEMM qkv (V^T fused epilogue) | flash-attn | GEMM proj.
// R18: v_transpose folded into gemm1's epilogue via 64KB LDS bounce --
// saves 33.6 MB HBM (qkv V-write + transpose read) + one kernel launch.
// ---------------------------------------------------------------------------

typedef __attribute__((ext_vector_type(8))) short bf16x8;
typedef __attribute__((ext_vector_type(4))) float f32x4;
typedef __attribute__((ext_vector_type(16))) float f32x16;
typedef __attribute__((ext_vector_type(2))) unsigned uint2v;

#define GLOBAL_AS __attribute__((address_space(1)))
#define LDS_AS __attribute__((address_space(3)))

__device__ __forceinline__ unsigned short f2b_rne(float f) {
  unsigned u = __float_as_uint(f);
  unsigned r = u + 0x7fffu + ((u >> 16) & 1u);
  return (unsigned short)(r >> 16);
}

__device__ __forceinline__ unsigned cvt_pk_bf16(float lo, float hi) {
  unsigned r;
  asm("v_cvt_pk_bf16_f32 %0, %1, %2" : "=v"(r) : "v"(lo), "v"(hi));
  return r;
}

__device__ __forceinline__ void gload_lds16(const void* g, void* l) {
  __builtin_amdgcn_global_load_lds((const GLOBAL_AS void*)g, (LDS_AS void*)l, 16, 0, 0);
}

// ---------------------------------------------------------------------------
// Fused fp32 -> bf16 conversion of all three inputs.
// ---------------------------------------------------------------------------
__global__ void fused_convert(const float* __restrict__ x,
                              const float* __restrict__ wqkv,
                              const float* __restrict__ wout,
                              unsigned short* __restrict__ xb,
                              unsigned short* __restrict__ wqkvb,
                              unsigned short* __restrict__ woutb) {
  const int nx = 8192 * 1024 / 4, nq = 3072 * 1024 / 4, nw = 1024 * 1024 / 4;
  const int ntot = nx + nq + nw;
  int i = blockIdx.x * blockDim.x + threadIdx.x;
  int stride = gridDim.x * blockDim.x;
  for (; i < ntot; i += stride) {
    const float* src;
    unsigned short* dst;
    int j = i;
    if (j < nx) {
      src = x; dst = xb;
    } else if ((j -= nx) < nq) {
      src = wqkv; dst = wqkvb;
    } else {
      j -= nq; src = wout; dst = woutb;
    }
    float4 v = reinterpret_cast<const float4*>(src)[j];
    ushort4 o;
    o.x = f2b_rne(v.x); o.y = f2b_rne(v.y);
    o.z = f2b_rne(v.z); o.w = f2b_rne(v.w);
    reinterpret_cast<ushort4*>(dst)[j] = o;
  }
}

// ---------------------------------------------------------------------------
// Big GEMM template: C[M,N] = A[M,1024] * B[N,1024]^T.
// 256x128 tile, 8 waves (4Mx2N), BK=64, mfma_32x32x16, counted-vmcnt loop.
// MODE 1 (qkv): bf16 out; V-blocks (n0>=2048) store TRANSPOSED into
// vt[bh][d][T] via a 64KB LDS bounce (coalesced both sides) and skip the
// qkv store.  MODE 0 (proj): fp32 out.
// ---------------------------------------------------------------------------
template <int N, int MODE>
__global__ __launch_bounds__(512)
void gemm_big(const unsigned short* __restrict__ A,
              const unsigned short* __restrict__ B,
              void* __restrict__ Cout, unsigned short* __restrict__ vt) {
  const int K = 1024;
  __shared__ __align__(16) unsigned short As[2][2][128 * 64];
  __shared__ __align__(16) unsigned short Bs[2][128 * 64];

  const int tid = threadIdx.x, wid = tid >> 6, lane = tid & 63;
  const int l31 = lane & 31, h = lane >> 5;
  const int NBX = N / 128;
  const int nwg8 = (int)gridDim.x >> 3;
  const int wgid = ((int)blockIdx.x & 7) * nwg8 + ((int)blockIdx.x >> 3);
  const int bx = wgid % NBX, by = wgid / NBX;
  const int m0 = by * 256, n0 = bx * 128;
  const int wr = wid >> 1, wc = wid & 1;

  auto stage = [&](int t, int buf) {
    const int k0 = t * 64;
    const int r8 = lane >> 3;
    const int blk = (lane & 7) ^ r8;
#pragma unroll
    for (int hh = 0; hh < 2; ++hh)
#pragma unroll
      for (int r = 0; r < 2; ++r) {
        int row = r * 64 + wid * 8 + r8;
        gload_lds16(A + (size_t)(m0 + hh * 128 + row) * K + k0 + blk * 8,
                    &As[buf][hh][r * 4096 + wid * 512]);
      }
#pragma unroll
    for (int r = 0; r < 2; ++r) {
      int row = r * 64 + wid * 8 + r8;
      gload_lds16(B + (size_t)(n0 + row) * K + k0 + blk * 8,
                  &Bs[buf][r * 4096 + wid * 512]);
    }
  };

  f32x16 acc[2][2] = {};

  stage(0, 0);

  int cur = 0;
  for (int t = 0; t < 16; ++t) {
    __builtin_amdgcn_s_barrier();
    if (t + 1 < 16) {
      stage(t + 1, cur ^ 1);
      asm volatile("s_waitcnt vmcnt(6)" ::: "memory");
    } else {
      asm volatile("s_waitcnt vmcnt(0)" ::: "memory");
    }
    __builtin_amdgcn_s_barrier();
    __builtin_amdgcn_sched_barrier(0);

    bf16x8 af[2][4], bfr[2][4];
#pragma unroll
    for (int mi = 0; mi < 2; ++mi) {
      int row = (wr & 1) * 64 + mi * 32 + l31;
#pragma unroll
      for (int ks = 0; ks < 4; ++ks) {
        int chunk = (ks * 2 + h) ^ (row & 7);
        af[mi][ks] = *(const bf16x8*)&As[cur][wr >> 1][row * 64 + chunk * 8];
      }
    }
#pragma unroll
    for (int ni = 0; ni < 2; ++ni) {
      int row = wc * 64 + ni * 32 + l31;
#pragma unroll
      for (int ks = 0; ks < 4; ++ks) {
        int chunk = (ks * 2 + h) ^ (row & 7);
        bfr[ni][ks] = *(const bf16x8*)&Bs[cur][row * 64 + chunk * 8];
      }
    }
    __builtin_amdgcn_s_setprio(1);
#pragma unroll
    for (int ks = 0; ks < 4; ++ks)
#pragma unroll
      for (int mi = 0; mi < 2; ++mi)
#pragma unroll
        for (int ni = 0; ni < 2; ++ni)
          acc[mi][ni] = __builtin_amdgcn_mfma_f32_32x32x16_bf16(
              af[mi][ks], bfr[ni][ks], acc[mi][ni], 0, 0, 0);
    __builtin_amdgcn_s_setprio(0);
    cur ^= 1;
  }

  if (MODE == 1 && n0 >= 2048) {
    // ---- fused V^T epilogue: acc -> LDS (swizzled) -> vt coalesced ----
    unsigned short(*Ts)[128] = (unsigned short(*)[128]) & As[0][0][0];
    __syncthreads();  // all waves done reading staged LDS
#pragma unroll
    for (int mi = 0; mi < 2; ++mi)
#pragma unroll
      for (int ni = 0; ni < 2; ++ni)
#pragma unroll
        for (int reg = 0; reg < 16; ++reg) {
          int row = wr * 64 + mi * 32 + (reg & 3) + 8 * (reg >> 2) + 4 * h;
          int col = wc * 64 + ni * 32 + l31;
          int c8 = (col >> 3) ^ (row & 15);
          Ts[row][c8 * 8 + (col & 7)] = f2b_rne(acc[mi][ni][reg]);
        }
    __syncthreads();
    const int chbase = n0 - 2048;
    const int bq = m0 >> 11, toff = m0 & 2047;
    const int ch = tid >> 2, tb = tid & 3;
    const int hh = (chbase + ch) >> 6, d = ch & 63;
    unsigned short* dst =
        vt + ((size_t)(bq * 16 + hh) * 64 + d) * 2048 + toff;
#pragma unroll
    for (int i = 0; i < 8; ++i) {
      int t0 = tb * 64 + i * 8;
      union { unsigned short s[8]; bf16x8 v; } o;
#pragma unroll
      for (int k = 0; k < 8; ++k) {
        int row = t0 + k;
        o.s[k] = Ts[row][(((ch >> 3) ^ (row & 15)) * 8) + (ch & 7)];
      }
      *(bf16x8*)(dst + t0) = o.v;
    }
  } else {
#pragma unroll
    for (int mi = 0; mi < 2; ++mi)
#pragma unroll
      for (int ni = 0; ni < 2; ++ni)
#pragma unroll
        for (int reg = 0; reg < 16; ++reg) {
          int row = m0 + wr * 64 + mi * 32 + (reg & 3) + 8 * (reg >> 2) + 4 * h;
          int col = n0 + wc * 64 + ni * 32 + l31;
          if (MODE == 1)
            ((unsigned short*)Cout)[(size_t)row * N + col] =
                f2b_rne(acc[mi][ni][reg]);
          else
            ((float*)Cout)[(size_t)row * N + col] = acc[mi][ni][reg];
        }
  }
}

// ---------------------------------------------------------------------------
// Flash attention fwd, causal; swapped-QK^T 32x32; 64 q-rows per wave.
// Super-tile staging: 128 kv rows per barrier-pair (2x64 compute passes).
// Static XCD map.  (unchanged R17: 79.0us measured)
// ---------------------------------------------------------------------------
__global__ __launch_bounds__(256, 2)
void attn_fwd(const unsigned short* __restrict__ qkv,
              const unsigned short* __restrict__ vt,
              unsigned short* __restrict__ out) {
  const int T = 2048, C3 = 3072;
  __shared__ __align__(16) unsigned short Ks[2][128][64];  // [kv][d] swizzled
  __shared__ __align__(16) unsigned short Vs[2][64][128];  // [d][kv] swizzled
  __shared__ float Bc[4][32];  // per-wave broadcast (wave-private)

  const int tid = threadIdx.x, w = tid >> 6, lane = tid & 63;
  const int l31 = lane & 31, h = lane >> 5;
  const int wgid = (blockIdx.x & 7) * 64 + (blockIdx.x >> 3);
  const int local = wgid & 63, xcd = wgid >> 6;
  const int qidx = local >> 3, bhl = local & 7;
  const int bh = xcd * 8 + bhl;
  const int qt = (qidx < 4) ? (7 - qidx) : (qidx - 4);
  const int b = bh >> 4, hed = bh & 15;
  const int qw = qt * 256 + w * 64;
  const size_t rowbase = (size_t)b * T * C3;
  const int hoff = hed * 64;
  const unsigned short* vbase = vt + (size_t)bh * 64 * 2048;
  const float c2 = 0.18033688f;  // 0.125 * log2(e)

  auto stageK = [&](int kv0, int buf) {
#pragma unroll
    for (int pp = 0; pp < 4; ++pp) {
      int chunk = w * 4 + pp;
      int row = chunk * 8 + (lane >> 3);
      int blk = (lane & 7) ^ (lane >> 3);
      gload_lds16(
          qkv + rowbase + (size_t)(kv0 + row) * C3 + 1024 + hoff + blk * 8,
          &Ks[buf][chunk * 8][0]);
    }
  };
  auto stageV = [&](int kv0, int buf) {
#pragma unroll
    for (int pp = 0; pp < 4; ++pp) {
      int c = w * 4 + pp;
      int d = c * 4 + (lane >> 4);
      int pos = lane & 15;
      int kvb = (pos & 8) | ((pos & 7) ^ (d & 7));
      gload_lds16(vbase + (size_t)d * 2048 + kv0 + kvb * 8,
                  &Vs[buf][c * 4][0]);
    }
  };

  bf16x8 qf0[4], qf1[4];
  {
    const unsigned short* qp0 =
        qkv + rowbase + (size_t)(qw + l31) * C3 + hoff + h * 8;
    const unsigned short* qp1 = qp0 + 32 * C3;
#pragma unroll
    for (int s = 0; s < 4; ++s) {
      qf0[s] = *(const bf16x8*)(qp0 + 16 * s);
      qf1[s] = *(const bf16x8*)(qp1 + 16 * s);
    }
  }

  f32x16 oacc0[2] = {}, oacc1[2] = {};
  float mr0 = -1e30f, mr1 = -1e30f, sum0 = 0.f, sum1 = 0.f;

  stageK(0, 0);
  stageV(0, 0);

  auto do_half = [&](f32x16 (&sacc)[2], int qx, float& mr, float& sm,
                     f32x16 (&oc)[2], bool first, int kvp, int cur, int vofs) {
    if (kvp + 64 > qx) {
      int q_abs = qx + l31;
#pragma unroll
      for (int kt = 0; kt < 2; ++kt)
#pragma unroll
        for (int r = 0; r < 16; ++r) {
          int kv_abs = kvp + kt * 32 + (r & 3) + 8 * (r >> 2) + 4 * h;
          if (kv_abs > q_abs) sacc[kt][r] = -1e30f;
        }
    }
    float mx[8];
#pragma unroll
    for (int g = 0; g < 8; ++g)
      mx[g] = fmaxf(fmaxf(sacc[g >> 2][(g & 3) * 4 + 0],
                          sacc[g >> 2][(g & 3) * 4 + 1]),
                    fmaxf(sacc[g >> 2][(g & 3) * 4 + 2],
                          sacc[g >> 2][(g & 3) * 4 + 3]));
    float tm = fmaxf(fmaxf(fmaxf(mx[0], mx[1]), fmaxf(mx[2], mx[3])),
                     fmaxf(fmaxf(mx[4], mx[5]), fmaxf(mx[6], mx[7])));
    tm = fmaxf(tm, __shfl_xor(tm, 32));
    if (first) {
      mr = tm;
    } else if (!__all(tm <= mr + 16.0f)) {
      float mnew = fmaxf(mr, tm);
      float corr = __builtin_amdgcn_exp2f((mr - mnew) * c2);
      sm *= corr;
      if (h == 0) Bc[w][l31] = corr;
      mr = mnew;
      asm volatile("s_waitcnt lgkmcnt(0)" ::: "memory");
#pragma unroll
      for (int r = 0; r < 16; ++r) {
        float cr = Bc[w][(r & 3) + 8 * (r >> 2) + 4 * h];
        oc[0][r] *= cr;
        oc[1][r] *= cr;
      }
    }
    float m2 = mr * c2;
    float s0 = 0.f, s1 = 0.f, s2 = 0.f, s3 = 0.f;
#pragma unroll
    for (int kt = 0; kt < 2; ++kt)
#pragma unroll
      for (int r = 0; r < 16; r += 4) {
        float p0 = __builtin_amdgcn_exp2f(fmaf(sacc[kt][r + 0], c2, -m2));
        float p1 = __builtin_amdgcn_exp2f(fmaf(sacc[kt][r + 1], c2, -m2));
        float p2 = __builtin_amdgcn_exp2f(fmaf(sacc[kt][r + 2], c2, -m2));
        float p3 = __builtin_amdgcn_exp2f(fmaf(sacc[kt][r + 3], c2, -m2));
        sacc[kt][r + 0] = p0; sacc[kt][r + 1] = p1;
        sacc[kt][r + 2] = p2; sacc[kt][r + 3] = p3;
        s0 += p0; s1 += p1; s2 += p2; s3 += p3;
      }
    float sl = (s0 + s1) + (s2 + s3);
    sm += sl + __shfl_xor(sl, 32);
    unsigned pk[16];
#pragma unroll
    for (int kt = 0; kt < 2; ++kt)
#pragma unroll
      for (int r = 0; r < 16; r += 2)
        pk[kt * 8 + (r >> 1)] = cvt_pk_bf16(sacc[kt][r], sacc[kt][r + 1]);
    __builtin_amdgcn_s_setprio(1);
#pragma unroll
    for (int sg = 0; sg < 4; ++sg) {
      const int kt = sg >> 1, s = sg & 1;
      const int base = kt * 8 + 4 * s;
      uint2v r02 = __builtin_amdgcn_permlane32_swap(pk[base], pk[base + 2],
                                                    false, false);
      uint2v r13 = __builtin_amdgcn_permlane32_swap(pk[base + 1], pk[base + 3],
                                                    false, false);
      union { unsigned u[4]; bf16x8 v; } Afr;
      Afr.u[0] = r02.x; Afr.u[1] = r13.x;
      Afr.u[2] = r02.y; Afr.u[3] = r13.y;
#pragma unroll
      for (int dt = 0; dt < 2; ++dt) {
        int d = dt * 32 + l31;
        int blk = (2 * sg + h) ^ (d & 7);
        bf16x8 vf = *(const bf16x8*)&Vs[cur][d][vofs + blk * 8];
        oc[dt] = __builtin_amdgcn_mfma_f32_32x32x16_bf16(Afr.v, vf,
                                                         oc[dt], 0, 0, 0);
      }
    }
    __builtin_amdgcn_s_setprio(0);
  };

  int cur = 0;
  const int nsup = 2 * qt + 2;  // super-tiles of 128 kv
  for (int t = 0; t < nsup; ++t) {
    const int kv0 = t * 128;
    __builtin_amdgcn_s_barrier();
    if (t + 1 < nsup) {
      stageK(kv0 + 128, cur ^ 1);
      stageV(kv0 + 128, cur ^ 1);
      asm volatile("s_waitcnt vmcnt(8)" ::: "memory");
    } else {
      asm volatile("s_waitcnt vmcnt(0)" ::: "memory");
    }
    __builtin_amdgcn_s_barrier();
    __builtin_amdgcn_sched_barrier(0);

#pragma unroll
    for (int p = 0; p < 2; ++p) {
      const int kvp = kv0 + p * 64;
      if (kvp <= qw) {
        f32x16 sacc0[2] = {}, sacc1[2] = {};
        __builtin_amdgcn_s_setprio(1);
#pragma unroll
        for (int s = 0; s < 4; ++s) {
#pragma unroll
          for (int kt = 0; kt < 2; ++kt) {
            int row = kt * 32 + l31;
            int blk = (2 * s + h) ^ (row & 7);
            bf16x8 kf = *(const bf16x8*)&Ks[cur][p * 64 + row][blk * 8];
            sacc0[kt] = __builtin_amdgcn_mfma_f32_32x32x16_bf16(
                kf, qf0[s], sacc0[kt], 0, 0, 0);
            sacc1[kt] = __builtin_amdgcn_mfma_f32_32x32x16_bf16(
                kf, qf1[s], sacc1[kt], 0, 0, 0);
          }
        }
        __builtin_amdgcn_s_setprio(0);
        const bool first = (t == 0 && p == 0);
        do_half(sacc0, qw, mr0, sum0, oacc0, first, kvp, cur, p * 64);
        do_half(sacc1, qw + 32, mr1, sum1, oacc1, first, kvp, cur, p * 64);
      }
    }
    cur ^= 1;
  }

  // epilogue (Bc is wave-private: lgkmcnt suffices, no barriers)
#pragma unroll
  for (int X = 0; X < 2; ++X) {
    float sm = X ? sum1 : sum0;
    if (h == 0) Bc[w][l31] = 1.0f / sm;
    asm volatile("s_waitcnt lgkmcnt(0)" ::: "memory");
#pragma unroll
    for (int r = 0; r < 16; ++r) {
      int ql = (r & 3) + 8 * (r >> 2) + 4 * h;
      float inv = Bc[w][ql];
      int q_abs = qw + 32 * X + ql;
#pragma unroll
      for (int dt = 0; dt < 2; ++dt) {
        float v = (X ? oacc1 : oacc0)[dt][r] * inv;
        out[(size_t)(b * T + q_abs) * 1024 + hoff + dt * 32 + l31] =
            f2b_rne(v);
      }
    }
  }
}

// ---------------------------------------------------------------------------
extern "C" void kernel_launch(void* const* d_in, const int* in_sizes, int n_in,
                              void* d_out, int out_size, void* d_ws,
                              size_t ws_size, hipStream_t stream) {
  const float* x = (const float*)d_in[0];      // [4,2048,1024]
  const float* w_qkv = (const float*)d_in[1];  // [3072,1024]
  const float* w_out = (const float*)d_in[2];  // [1024,1024]
  float* out = (float*)d_out;                  // [4,2048,1024] fp32

  const int M = 8192, C = 1024, C3 = 3072;

  unsigned short* xb = (unsigned short*)d_ws;      // M*C  (reused as attno)
  unsigned short* wqkvb = xb + (size_t)M * C;      // C3*C
  unsigned short* woutb = wqkvb + (size_t)C3 * C;  // C*C
  unsigned short* qkv = woutb + (size_t)C * C;     // M*C3 (V region unused)
  unsigned short* vtb = qkv + (size_t)M * C3;      // B*H*64*T = M*C
  unsigned short* attno = xb;                      // alias: xb dead post-GEMM1

  fused_convert<<<2048, 256, 0, stream>>>(x, w_qkv, w_out, xb, wqkvb, woutb);

  gemm_big<3072, 1><<<768, 512, 0, stream>>>(xb, wqkvb, qkv, vtb);

  attn_fwd<<<512, 256, 0, stream>>>(qkv, vtb, attno);

  gemm_big<1024, 0><<<256, 512, 0, stream>>>(attno, woutb, out, nullptr);
}